// Round 11
// baseline (398.591 us; speedup 1.0000x reference)
//
#include <hip/hip_runtime.h>
#include <stdint.h>

#define NHEADS 32
#define DHEAD  128
#define LQ     2048
#define PAGE   16
#define QTILE  64     // q rows per q-tile (4 waves x 16)
#define NQT    32     // q-tiles total
#define KVB    64     // kv tokens per staged tile (2 halves of 32)
#define KPAD   136    // 128 + 8 f16 pad for Ks rows

typedef _Float16 f16x8 __attribute__((ext_vector_type(8)));
typedef _Float16 f16x2v __attribute__((ext_vector_type(2)));
typedef float    f32x4 __attribute__((ext_vector_type(4)));

__global__ __launch_bounds__(256, 2)
void paged_attn_kernel(const float* __restrict__ q,
                       const int*   __restrict__ Kp,      // int8 widened to int32
                       const int*   __restrict__ Vp,      // int8 widened to int32
                       const float* __restrict__ Kscale,  // f16 widened to f32
                       const float* __restrict__ Vscale,
                       const int*   __restrict__ pages,
                       float* __restrict__ out)
{
    __shared__ _Float16 Ks[KVB][KPAD];                 // 64 kv rows, dequantized
    __shared__ __align__(16) _Float16 Vt[2][DHEAD][32];// V^T per 32-half, swizzled

    const int tid  = threadIdx.x;
    const int w    = tid >> 6;
    const int lane = tid & 63;
    const int g    = lane >> 4;       // 0..3
    const int c    = lane & 15;       // 0..15

    const int bx = blockIdx.x;
    const int h  = bx & (NHEADS - 1);
    const int p  = bx >> 5;                  // pair id 0..15
    const int qa = p, qb = NQT - 1 - p;      // balanced causal pair
    const int q0a = qa * QTILE, q0b = qb * QTILE;

    const float qscale = 0.08838834764831845f * 1.44269504088896340736f;

    // ---- Q fragments (A/B-layout: row/col = lane&15, k = (lane>>4)*8+i) ----
    f16x8 qfa[4], qfb[4];
    {
        const float* qpa = q + ((size_t)h * LQ + q0a + w * 16 + c) * DHEAD;
        const float* qpb = q + ((size_t)h * LQ + q0b + w * 16 + c) * DHEAD;
        #pragma unroll
        for (int t = 0; t < 4; ++t)
            #pragma unroll
            for (int i = 0; i < 8; ++i) {
                qfa[t][i] = (_Float16)(qpa[t * 32 + g * 8 + i] * qscale);
                qfb[t][i] = (_Float16)(qpb[t * 32 + g * 8 + i] * qscale);
            }
    }

    f32x4 oaccA[8], oaccB[8];
    #pragma unroll
    for (int d = 0; d < 8; ++d) { oaccA[d] = (f32x4){0,0,0,0}; oaccB[d] = (f32x4){0,0,0,0}; }
    float mA = -1e30f, lA = 0.f, mB = -1e30f, lB = 0.f;

    const int ntiles = qb + 1;               // 64-token tiles for the heavy q-tile
    const int skv = tid >> 3;                // K staging: kv row in half (0..31)
    const int sa  = tid & 7;                 // K staging: 16-dim chunk (0..7)
    const int tp  = tid >> 4;                // V staging: token pair (0..15)
    const int do8 = (tid & 15) * 8;          // V staging: dcol octet base

    int4 kr[8], vr[8];                       // staged regs: K 32 ints, V 32 ints
    float ksc2[2], vsc2[2];

    auto issue = [&](int t) {
        #pragma unroll
        for (int hh = 0; hh < 2; ++hh) {
            const int rowk = t * KVB + hh * 32 + skv;
            const int pgk  = pages[rowk >> 4];
            const size_t bk = (((size_t)pgk * PAGE + (rowk & 15)) * NHEADS + h) * DHEAD + sa * 16;
            const int4* kp4 = (const int4*)(Kp + bk);
            #pragma unroll
            for (int j = 0; j < 4; ++j) kr[hh * 4 + j] = kp4[j];
            ksc2[hh] = Kscale[pgk * NHEADS + h];

            const int rowv = t * KVB + hh * 32 + 2 * tp;   // even -> pair in same page
            const int pgv  = pages[rowv >> 4];
            const size_t bv = (((size_t)pgv * PAGE + (rowv & 15)) * NHEADS + h) * DHEAD + do8;
            const int4* vp4  = (const int4*)(Vp + bv);
            const int4* vp4b = (const int4*)(Vp + bv + (size_t)NHEADS * DHEAD);
            vr[hh * 4 + 0] = vp4[0];  vr[hh * 4 + 1] = vp4[1];
            vr[hh * 4 + 2] = vp4b[0]; vr[hh * 4 + 3] = vp4b[1];
            vsc2[hh] = Vscale[pgv * NHEADS + h];
        }
    };

    auto stage = [&]() {
        #pragma unroll
        for (int hh = 0; hh < 2; ++hh) {
            const int* ki = (const int*)&kr[hh * 4];
            const float ks = ksc2[hh];
            f16x8 klo, khi;
            #pragma unroll
            for (int i = 0; i < 8; ++i) {
                klo[i] = (_Float16)((float)ki[i]     * ks);
                khi[i] = (_Float16)((float)ki[8 + i] * ks);
            }
            *(f16x8*)&Ks[hh * 32 + skv][sa * 16]     = klo;
            *(f16x8*)&Ks[hh * 32 + skv][sa * 16 + 8] = khi;

            const int* vi = (const int*)&vr[hh * 4];   // [0..7]=tok even, [8..15]=tok odd
            const float vs = vsc2[hh];
            char* vtb = (char*)&Vt[hh][0][0];
            #pragma unroll
            for (int j = 0; j < 8; ++j) {
                const int dcol = do8 + j;
                f16x2v pv;
                pv[0] = (_Float16)((float)vi[j]     * vs);
                pv[1] = (_Float16)((float)vi[8 + j] * vs);
                unsigned off = (unsigned)(dcol * 64 + tp * 4);
                off ^= (unsigned)(((dcol >> 3) & 7) << 4);   // same swizzle as reads
                *(int*)(vtb + off) = __builtin_bit_cast(int, pv);
            }
        }
    };

    // Swapped-QK^T over 64 kv: lane holds S[q=qW+c][kv=kv0+16*idx+4g+r], idx=0..3
    auto compute = [&](int kv0, const f16x8* qf, int q0t,
                       f32x4* oacc, float& mr, float& lr) {
        f32x4 s[4];
        #pragma unroll
        for (int idx = 0; idx < 4; ++idx) {
            s[idx] = (f32x4){0, 0, 0, 0};
            #pragma unroll
            for (int t = 0; t < 4; ++t) {
                f16x8 kf = *(const f16x8*)&Ks[idx * 16 + c][t * 32 + g * 8];
                s[idx] = __builtin_amdgcn_mfma_f32_16x16x32_f16(kf, qf[t], s[idx], 0, 0, 0);
            }
        }
        // causal mask
        const int dq = (q0t + w * 16 + c) - (kv0 + 4 * g);
        #pragma unroll
        for (int idx = 0; idx < 4; ++idx)
            #pragma unroll
            for (int r = 0; r < 4; ++r)
                if (r > dq - 16 * idx) s[idx][r] = -1e30f;
        // row max (15 in-lane + 2 shuffles)
        float tm = -1e30f;
        #pragma unroll
        for (int idx = 0; idx < 4; ++idx)
            #pragma unroll
            for (int r = 0; r < 4; ++r) tm = fmaxf(tm, s[idx][r]);
        tm = fmaxf(tm, __shfl_xor(tm, 16, 64));
        tm = fmaxf(tm, __shfl_xor(tm, 32, 64));

        const bool fast = __all(tm <= mr);   // T13: exact defer (alpha == 1)
        float mn = mr;
        float alpha = 1.f;
        if (!fast) {
            mn = fmaxf(mr, tm);
            alpha = exp2f(mr - mn);
            mr = mn;
        }
        // P = exp2(S - mn), row sum
        float rs = 0.f;
        #pragma unroll
        for (int idx = 0; idx < 4; ++idx)
            #pragma unroll
            for (int r = 0; r < 4; ++r) {
                s[idx][r] = exp2f(s[idx][r] - mn);
                rs += s[idx][r];
            }
        rs += __shfl_xor(rs, 16, 64);
        rs += __shfl_xor(rs, 32, 64);
        if (fast) {
            lr += rs;
        } else {
            lr = lr * alpha + rs;
            float aR[4];
            #pragma unroll
            for (int r = 0; r < 4; ++r) aR[r] = __shfl(alpha, 20 * g + r, 64);
            #pragma unroll
            for (int d = 0; d < 8; ++d)
                #pragma unroll
                for (int r = 0; r < 4; ++r)
                    oacc[d][r] *= aR[r];
        }
        // ---- P redistribution per 32-half (R7 derivation), then PV ----
        f16x8 pa[2];
        #pragma unroll
        for (int hh = 0; hh < 2; ++hh) {
            f16x2v t0, t1, t2, t3;
            t0[0] = (_Float16)s[2*hh][0];   t0[1] = (_Float16)s[2*hh][1];
            t1[0] = (_Float16)s[2*hh][2];   t1[1] = (_Float16)s[2*hh][3];
            t2[0] = (_Float16)s[2*hh+1][0]; t2[1] = (_Float16)s[2*hh+1][1];
            t3[0] = (_Float16)s[2*hh+1][2]; t3[1] = (_Float16)s[2*hh+1][3];
            const int w00 = __builtin_bit_cast(int, t0);
            const int w01 = __builtin_bit_cast(int, t1);
            const int w10 = __builtin_bit_cast(int, t2);
            const int w11 = __builtin_bit_cast(int, t3);
            const int srcL = ((g & 1) << 5) | c;
            const int srcH = srcL + 16;
            const int e0A = __shfl(w00, srcL, 64), e0B = __shfl(w10, srcL, 64);
            const int e1A = __shfl(w01, srcL, 64), e1B = __shfl(w11, srcL, 64);
            const int e2A = __shfl(w00, srcH, 64), e2B = __shfl(w10, srcH, 64);
            const int e3A = __shfl(w01, srcH, 64), e3B = __shfl(w11, srcH, 64);
            const bool hi = g >= 2;
            uint4 aw;
            aw.x = (unsigned)(hi ? e0B : e0A);
            aw.y = (unsigned)(hi ? e1B : e1A);
            aw.z = (unsigned)(hi ? e2B : e2A);
            aw.w = (unsigned)(hi ? e3B : e3A);
            pa[hh] = __builtin_bit_cast(f16x8, aw);
        }
        #pragma unroll
        for (int d = 0; d < 8; ++d) {
            const int dcol = d * 16 + c;
            unsigned off = (unsigned)(dcol * 64 + g * 16);
            off ^= (unsigned)(((dcol >> 3) & 7) << 4);
            f16x8 vfL = *(const f16x8*)((const char*)&Vt[0][0][0] + off);
            f16x8 vfH = *(const f16x8*)((const char*)&Vt[1][0][0] + off);
            oacc[d] = __builtin_amdgcn_mfma_f32_16x16x32_f16(pa[0], vfL, oacc[d], 0, 0, 0);
            oacc[d] = __builtin_amdgcn_mfma_f32_16x16x32_f16(pa[1], vfH, oacc[d], 0, 0, 0);
        }
    };

    issue(0);
    for (int t = 0; t < ntiles; ++t) {
        const int kv0 = t * KVB;
        stage();                              // regs -> LDS (reads kr/vr)
        __syncthreads();
        if (t + 1 < ntiles) issue(t + 1);     // overwrite kr/vr (WAR after stage)

        compute(kv0, qfb, q0b, oaccB, mB, lB);                 // B active every tile
        if (kv0 <= q0a + w * 16 + 15)                          // A active t <= p
            compute(kv0, qfa, q0a, oaccA, mA, lA);

        __syncthreads();
    }

    // ---- normalize + store (l for row q=4g+r lives in lane 20g+r) ----
    float iA[4], iB[4];
    #pragma unroll
    for (int r = 0; r < 4; ++r) {
        iA[r] = 1.f / __shfl(lA, 20 * g + r, 64);
        iB[r] = 1.f / __shfl(lB, 20 * g + r, 64);
    }
    const int qgA = q0a + w * 16 + g * 4;
    const int qgB = q0b + w * 16 + g * 4;
    #pragma unroll
    for (int d = 0; d < 8; ++d)
        #pragma unroll
        for (int r = 0; r < 4; ++r) {
            out[((size_t)h * LQ + qgA + r) * DHEAD + d * 16 + c] = oaccA[d][r] * iA[r];
            out[((size_t)h * LQ + qgB + r) * DHEAD + d * 16 + c] = oaccB[d][r] * iB[r];
        }
}

extern "C" void kernel_launch(void* const* d_in, const int* in_sizes, int n_in,
                              void* d_out, int out_size, void* d_ws, size_t ws_size,
                              hipStream_t stream) {
    (void)in_sizes; (void)n_in; (void)d_ws; (void)ws_size; (void)out_size;
    const float* qp = (const float*)d_in[0];
    const int*   kp = (const int*)d_in[1];    // int8 -> int32 per harness contract
    const int*   vp = (const int*)d_in[2];
    const float* ks = (const float*)d_in[3];  // f16 -> f32 per harness contract
    const float* vs = (const float*)d_in[4];
    const int*   pg = (const int*)d_in[5];
    float*       op = (float*)d_out;

    dim3 grid(NHEADS * (NQT / 2));   // 512 balanced pair-blocks
    dim3 block(256);
    paged_attn_kernel<<<grid, block, 0, stream>>>(qp, kp, vp, ks, vs, pg, op);
}

// Round 12
// 259.078 us; speedup vs baseline: 1.5385x; 1.5385x over previous
//
#include <hip/hip_runtime.h>
#include <stdint.h>

#define NHEADS 32
#define DHEAD  128
#define LQ     2048
#define PAGE   16
#define QTILE  64     // q rows per q-tile (4 waves x 16)
#define NQT    32     // q-tiles total
#define KVB    32     // kv tokens per staged tile
#define KPAD   136    // 128 + 8 f16 pad

typedef _Float16 f16x8 __attribute__((ext_vector_type(8)));
typedef _Float16 f16x2v __attribute__((ext_vector_type(2)));
typedef float    f32x4 __attribute__((ext_vector_type(4)));

__global__ __launch_bounds__(256, 2)
void paged_attn_kernel(const float* __restrict__ q,
                       const int*   __restrict__ Kp,      // int8 widened to int32
                       const int*   __restrict__ Vp,      // int8 widened to int32
                       const float* __restrict__ Kscale,  // f16 widened to f32
                       const float* __restrict__ Vscale,
                       const int*   __restrict__ pages,
                       float* __restrict__ out)
{
    __shared__ _Float16 Ks[KVB][KPAD];                 // K tile, dequantized
    __shared__ __align__(16) _Float16 Vt[DHEAD][KVB];  // V^T, dequantized, swizzled

    const int tid  = threadIdx.x;
    const int w    = tid >> 6;
    const int lane = tid & 63;
    const int g    = lane >> 4;       // 0..3
    const int c    = lane & 15;       // 0..15

    const int bx = blockIdx.x;
    const int h  = bx & (NHEADS - 1);
    const int p  = bx >> 5;                  // pair id 0..15
    const int qa = p, qb = NQT - 1 - p;      // balanced causal pair
    const int q0a = qa * QTILE, q0b = qb * QTILE;

    const float qscale = 0.08838834764831845f * 1.44269504088896340736f;

    // ---- Q fragments (A/B-layout: row/col = lane&15, k = (lane>>4)*8+i) ----
    f16x8 qfa[4], qfb[4];
    {
        const float* qpa = q + ((size_t)h * LQ + q0a + w * 16 + c) * DHEAD;
        const float* qpb = q + ((size_t)h * LQ + q0b + w * 16 + c) * DHEAD;
        #pragma unroll
        for (int t = 0; t < 4; ++t)
            #pragma unroll
            for (int i = 0; i < 8; ++i) {
                qfa[t][i] = (_Float16)(qpa[t * 32 + g * 8 + i] * qscale);
                qfb[t][i] = (_Float16)(qpb[t * 32 + g * 8 + i] * qscale);
            }
    }

    f32x4 oaccA[8], oaccB[8];
    #pragma unroll
    for (int d = 0; d < 8; ++d) { oaccA[d] = (f32x4){0,0,0,0}; oaccB[d] = (f32x4){0,0,0,0}; }
    float mA = -1e30f, lA = 0.f, mB = -1e30f, lB = 0.f;

    const int ntiles = 2 * qb + 2;
    const int skv = tid >> 3;                // K staging: kv row 0..31
    const int sa  = tid & 7;                 // K staging: 16-dim chunk 0..7
    const int tp  = tid >> 4;                // V staging: token pair 0..15
    const int do8 = (tid & 15) * 8;          // V staging: dcol octet base

    int4 kr[4], vr[4];                       // staged regs (32 ints total - no spill)
    float ksr = 0.f, vsr = 0.f;

    auto issue = [&](int t) {
        const int rowk = t * KVB + skv;
        const int pgk  = pages[rowk >> 4];
        const size_t bk = (((size_t)pgk * PAGE + (rowk & 15)) * NHEADS + h) * DHEAD + sa * 16;
        const int4* kp4 = (const int4*)(Kp + bk);
        #pragma unroll
        for (int j = 0; j < 4; ++j) kr[j] = kp4[j];
        ksr = Kscale[pgk * NHEADS + h];

        const int rowv = t * KVB + 2 * tp;               // even -> pair within one page
        const int pgv  = pages[rowv >> 4];
        const size_t bv = (((size_t)pgv * PAGE + (rowv & 15)) * NHEADS + h) * DHEAD + do8;
        const int4* vp4  = (const int4*)(Vp + bv);
        const int4* vp4b = (const int4*)(Vp + bv + (size_t)NHEADS * DHEAD);
        vr[0] = vp4[0];  vr[1] = vp4[1];                 // token 2tp, dcols do8..do8+7
        vr[2] = vp4b[0]; vr[3] = vp4b[1];                // token 2tp+1
        vsr = Vscale[pgv * NHEADS + h];
    };

    auto stage = [&]() {
        const int* ki = (const int*)kr;
        f16x8 klo, khi;
        #pragma unroll
        for (int i = 0; i < 8; ++i) {
            klo[i] = (_Float16)((float)ki[i]     * ksr);
            khi[i] = (_Float16)((float)ki[8 + i] * ksr);
        }
        *(f16x8*)&Ks[skv][sa * 16]     = klo;
        *(f16x8*)&Ks[skv][sa * 16 + 8] = khi;

        const int* vi = (const int*)vr;      // [0..7]=token even, [8..15]=token odd
        char* vtb = (char*)&Vt[0][0];
        #pragma unroll
        for (int j = 0; j < 8; ++j) {
            const int dcol = do8 + j;
            f16x2v pv;
            pv[0] = (_Float16)((float)vi[j]     * vsr);
            pv[1] = (_Float16)((float)vi[8 + j] * vsr);
            unsigned off = (unsigned)(dcol * (KVB * 2) + tp * 4);
            off ^= (unsigned)(((dcol >> 3) & 7) << 4);   // same swizzle as reads
            *(int*)(vtb + off) = __builtin_bit_cast(int, pv);
        }
    };

    // Swapped-QK^T: lane holds S[q=qW+c][kv=kv0+16nt+4g+r]
    auto compute = [&](int kv0, const f16x8* qf, int q0t,
                       f32x4* oacc, float& mr, float& lr) {
        f32x4 s0 = (f32x4){0,0,0,0}, s1 = (f32x4){0,0,0,0};
        __builtin_amdgcn_s_setprio(1);
        #pragma unroll
        for (int t = 0; t < 4; ++t) {
            f16x8 kf0 = *(const f16x8*)&Ks[c][t * 32 + g * 8];
            f16x8 kf1 = *(const f16x8*)&Ks[16 + c][t * 32 + g * 8];
            s0 = __builtin_amdgcn_mfma_f32_16x16x32_f16(kf0, qf[t], s0, 0, 0, 0);
            s1 = __builtin_amdgcn_mfma_f32_16x16x32_f16(kf1, qf[t], s1, 0, 0, 0);
        }
        __builtin_amdgcn_s_setprio(0);
        // causal mask: kv = kv0 + 16nt + 4g + r  >  q = q0t + w*16 + c -> masked
        const int dq = (q0t + w * 16 + c) - (kv0 + 4 * g);
        #pragma unroll
        for (int r = 0; r < 4; ++r) {
            if (r > dq)      s0[r] = -1e30f;
            if (r > dq - 16) s1[r] = -1e30f;
        }
        float tm = fmaxf(fmaxf(fmaxf(s0[0], s0[1]), fmaxf(s0[2], s0[3])),
                         fmaxf(fmaxf(s1[0], s1[1]), fmaxf(s1[2], s1[3])));
        tm = fmaxf(tm, __shfl_xor(tm, 16, 64));
        tm = fmaxf(tm, __shfl_xor(tm, 32, 64));

        const bool fast = __all(tm <= mr);   // T13: exact defer (alpha == 1)
        float mn = mr;
        if (!fast) {
            mn = fmaxf(mr, tm);
            const float alpha = exp2f(mr - mn);
            mr = mn;
            float aR[4];
            #pragma unroll
            for (int r = 0; r < 4; ++r) aR[r] = __shfl(alpha, 20 * g + r, 64);
            lr *= alpha;                     // fold alpha into l here; rs added below
            #pragma unroll
            for (int d = 0; d < 8; ++d)
                #pragma unroll
                for (int r = 0; r < 4; ++r)
                    oacc[d][r] *= aR[r];
        }
        float p0[4], p1[4];
        float rs = 0.f;
        #pragma unroll
        for (int r = 0; r < 4; ++r) {
            p0[r] = exp2f(s0[r] - mn);
            p1[r] = exp2f(s1[r] - mn);
            rs += p0[r] + p1[r];
        }
        rs += __shfl_xor(rs, 16, 64);
        rs += __shfl_xor(rs, 32, 64);
        lr += rs;
        // ---- P redistribution to PV A-frag (R7 derivation, in-register) ----
        f16x2v t0, t1, t2, t3;
        t0[0] = (_Float16)p0[0]; t0[1] = (_Float16)p0[1];
        t1[0] = (_Float16)p0[2]; t1[1] = (_Float16)p0[3];
        t2[0] = (_Float16)p1[0]; t2[1] = (_Float16)p1[1];
        t3[0] = (_Float16)p1[2]; t3[1] = (_Float16)p1[3];
        const int w00 = __builtin_bit_cast(int, t0);
        const int w01 = __builtin_bit_cast(int, t1);
        const int w10 = __builtin_bit_cast(int, t2);
        const int w11 = __builtin_bit_cast(int, t3);
        const int srcL = ((g & 1) << 5) | c;
        const int srcH = srcL + 16;
        const int e0A = __shfl(w00, srcL, 64), e0B = __shfl(w10, srcL, 64);
        const int e1A = __shfl(w01, srcL, 64), e1B = __shfl(w11, srcL, 64);
        const int e2A = __shfl(w00, srcH, 64), e2B = __shfl(w10, srcH, 64);
        const int e3A = __shfl(w01, srcH, 64), e3B = __shfl(w11, srcH, 64);
        const bool hi = g >= 2;
        uint4 aw;
        aw.x = (unsigned)(hi ? e0B : e0A);
        aw.y = (unsigned)(hi ? e1B : e1A);
        aw.z = (unsigned)(hi ? e2B : e2A);
        aw.w = (unsigned)(hi ? e3B : e3A);
        const f16x8 pa = __builtin_bit_cast(f16x8, aw);
        // ---- PV: vf[i] = Vt[dcol=d*16+c][kv=g*8+i] (swizzled) ----
        __builtin_amdgcn_s_setprio(1);
        #pragma unroll
        for (int d = 0; d < 8; ++d) {
            const int dcol = d * 16 + c;
            unsigned off = (unsigned)(dcol * (KVB * 2) + g * 16);
            off ^= (unsigned)(((dcol >> 3) & 7) << 4);
            f16x8 vf = *(const f16x8*)((const char*)&Vt[0][0] + off);
            oacc[d] = __builtin_amdgcn_mfma_f32_16x16x32_f16(pa, vf, oacc[d], 0, 0, 0);
        }
        __builtin_amdgcn_s_setprio(0);
    };

    issue(0);
    for (int t = 0; t < ntiles; ++t) {
        const int kv0 = t * KVB;
        stage();                              // regs -> LDS (reads kr/vr)
        __syncthreads();
        if (t + 1 < ntiles) issue(t + 1);     // overwrite kr/vr (WAR after stage)

        compute(kv0, qfb, q0b, oaccB, mB, lB);                 // B active every tile
        if (kv0 <= q0a + w * 16 + 15)                          // A active early tiles
            compute(kv0, qfa, q0a, oaccA, mA, lA);

        __syncthreads();
    }

    // ---- normalize + store (l for row q=4g+r lives in lane 20g+r) ----
    float iA[4], iB[4];
    #pragma unroll
    for (int r = 0; r < 4; ++r) {
        iA[r] = 1.f / __shfl(lA, 20 * g + r, 64);
        iB[r] = 1.f / __shfl(lB, 20 * g + r, 64);
    }
    const int qgA = q0a + w * 16 + g * 4;
    const int qgB = q0b + w * 16 + g * 4;
    #pragma unroll
    for (int d = 0; d < 8; ++d)
        #pragma unroll
        for (int r = 0; r < 4; ++r) {
            out[((size_t)h * LQ + qgA + r) * DHEAD + d * 16 + c] = oaccA[d][r] * iA[r];
            out[((size_t)h * LQ + qgB + r) * DHEAD + d * 16 + c] = oaccB[d][r] * iB[r];
        }
}

extern "C" void kernel_launch(void* const* d_in, const int* in_sizes, int n_in,
                              void* d_out, int out_size, void* d_ws, size_t ws_size,
                              hipStream_t stream) {
    (void)in_sizes; (void)n_in; (void)d_ws; (void)ws_size; (void)out_size;
    const float* qp = (const float*)d_in[0];
    const int*   kp = (const int*)d_in[1];    // int8 -> int32 per harness contract
    const int*   vp = (const int*)d_in[2];
    const float* ks = (const float*)d_in[3];  // f16 -> f32 per harness contract
    const float* vs = (const float*)d_in[4];
    const int*   pg = (const int*)d_in[5];
    float*       op = (float*)d_out;

    dim3 grid(NHEADS * (NQT / 2));   // 512 balanced pair-blocks
    dim3 block(256);
    paged_attn_kernel<<<grid, block, 0, stream>>>(qp, kp, vp, ks, vs, pg, op);
}